// Round 6
// baseline (185.005 us; speedup 1.0000x reference)
//
#include <hip/hip_runtime.h>
#include <math.h>

// Problem constants (from setup_inputs): N=8, H=768, W=360, D=512
#define N_IMG 8
#define H 768
#define W 360
#define D 512
#define SY 383.5f         // (H-1)/2
#define SC 0.00436332312998582394f  // pi/(2W) = pi/720
#define NC 24             // 768/32 m-chunks
#define IPAD 384          // i dimension padded 360 -> 384

typedef __fp16 h2 __attribute__((ext_vector_type(2)));
typedef short short8 __attribute__((ext_vector_type(8)));   // 8 bf16 (4 VGPRs)
typedef float f32x4 __attribute__((ext_vector_type(4)));

// fp32 -> bf16 pair, round-to-nearest-even, packed into one uint
__device__ inline unsigned bf16pair(float a, float b) {
    unsigned ua = __builtin_bit_cast(unsigned, a);
    unsigned ub = __builtin_bit_cast(unsigned, b);
    ua += 0x7FFFu + ((ua >> 16) & 1u);
    ub += 0x7FFFu + ((ub >> 16) & 1u);
    return (ua >> 16) | (ub & 0xFFFF0000u);
}

__device__ inline uint4 sel4(bool b, uint4 x, uint4 y) {   // b ? x : y, 4 cndmask
    return make_uint4(b ? x.x : y.x, b ? x.y : y.y, b ? x.z : y.z, b ? x.w : y.w);
}

// ---------------------------------------------------------------------------
// Kernel 1: g[m] = (1/H) sum_k hG[k] * cos(2*pi*k*m/H)
// ---------------------------------------------------------------------------
__global__ void build_g_kernel(const float* __restrict__ hG, float* __restrict__ g) {
    int m = blockIdx.x;          // 0..767
    int lane = threadIdx.x;      // 0..63
    float s = 0.f;
#pragma unroll
    for (int q = 0; q < 12; ++q) {
        int k = lane + 64 * q;
        int prod = (k * m) % H;  // exact periodic reduction
        float angr = (float)prod * 0.00818123086872313911f;  // 2*pi/768
        s += hG[k] * cosf(angr);
    }
#pragma unroll
    for (int off = 32; off > 0; off >>= 1) s += __shfl_down(s, off);
    if (lane == 0) g[m] = s * (1.0f / (float)H);
}

// ---------------------------------------------------------------------------
// Kernel 2 (fused): blocks 0-39 build the MFMA B-frag table
// Bg[(t*4+j)*64+L] (n = j*16+(L&15), k = 32t+(L>>4)*8+s, val g[(n+128-k)%H]);
// block 40 builds per-angle constants ang[i] = (cos*r, -sin*r).
// ---------------------------------------------------------------------------
#define KSTEPS 10          // 10 x 32 = K 320 band

__global__ void build_angbg_kernel(const float* __restrict__ g, uint4* __restrict__ Bg,
                                   float2* __restrict__ ang) {
    int b = blockIdx.x;
    int t = threadIdx.x;
    if (b < 40) {
        int idx = b * 64 + t;       // 0..2559
        int L  = idx & 63;
        int tj = idx >> 6;          // t*4 + j
        int nn = (tj & 3) * 16 + (L & 15);
        int kb = (tj >> 2) * 32 + (L >> 4) * 8;
        float bf[8];
#pragma unroll
        for (int s = 0; s < 8; ++s) {
            int d = nn + 128 - (kb + s);
            d += (d < 0) ? H : 0;
            bf[s] = g[d];
        }
        Bg[idx] = (uint4){bf16pair(bf[0], bf[1]), bf16pair(bf[2], bf[3]),
                          bf16pair(bf[4], bf[5]), bf16pair(bf[6], bf[7])};
    } else {
#pragma unroll
        for (int q = 0; q < 6; ++q) {
            int i = t + 64 * q;
            if (i < W) {
                float th = (float)i * 0.00872664625997164788f;  // pi/360
                float r = SY / 384.0f;
                ang[i] = make_float2(cosf(th) * r, -sinf(th) * r);
            }
        }
    }
}

// ---------------------------------------------------------------------------
// Kernel 3: A-matrix transpose + bf16 pack (+ fused output zeroing).
// px = (tx_i+1)*sx == i exactly -> rc[n][i][m] = radon[n][m][i]: pure
// transpose. Block (i-tile 64, chunk c, image n): coalesced float4 row loads
// -> LDS (pad 65) -> transposed bf16x8 pack -> contiguous uint4 store.
// Blocks with flat id < 1024 also zero 2 KB of the output (atomic target).
// Grid (6, 24, 8) = 1152 blocks x 256 thr.
// ---------------------------------------------------------------------------
__global__ __launch_bounds__(256)
void build_rc_kernel(const float* __restrict__ radon, uint4* __restrict__ rcC,
                     float4* __restrict__ out4) {
    __shared__ float xs[32][65];   // 8.3 KB

    const int i0 = blockIdx.x * 64;
    const int c  = blockIdx.y;
    const int n  = blockIdx.z;
    const int tid = threadIdx.x;

    // fused zero of the atomic output (1024 blocks x 512 float4 = full 8 MB)
    {
        int flat = ((n * NC) + c) * 6 + blockIdx.x;
        if (flat < 1024) {
            out4[flat * 512 + tid]       = make_float4(0.f, 0.f, 0.f, 0.f);
            out4[flat * 512 + 256 + tid] = make_float4(0.f, 0.f, 0.f, 0.f);
        }
    }

    // load radon[m = 32c + mr][i0 + lane8*8 .. +8) coalesced
    {
        int mr    = tid >> 3;      // 0..31
        int lane8 = tid & 7;
        int ib = i0 + lane8 * 8;
        const float* src = radon + ((size_t)n * H + 32 * c + mr) * W + ib;
        float4 v0, v1;
        if (ib + 7 < W) {          // 360 % 8 == 0: tiles all-valid or all-invalid
            v0 = *(const float4*)src;
            v1 = *(const float4*)(src + 4);
        } else {
            v0 = make_float4(0.f, 0.f, 0.f, 0.f);
            v1 = make_float4(0.f, 0.f, 0.f, 0.f);
        }
        *(float4*)&xs[mr][lane8 * 8]     = v0;
        *(float4*)&xs[mr][lane8 * 8 + 4] = v1;
    }
    __syncthreads();

    // transposed pack: 8 m-values (oct) for angle i0+il
    const int il  = tid >> 2;      // 0..63
    const int oct = tid & 3;
    float v[8];
#pragma unroll
    for (int s = 0; s < 8; ++s) v[s] = xs[oct * 8 + s][il];
    uint4 pk = {bf16pair(v[0], v[1]), bf16pair(v[2], v[3]),
                bf16pair(v[4], v[5]), bf16pair(v[6], v[7])};
    rcC[(((size_t)n * NC + c) * IPAD + i0 + il) * 4 + oct] = pk;
}

// ---------------------------------------------------------------------------
// Kernel 4: banded circulant filtering, barrier-free MFMA GEMM.
// ONE 512-thread block covers all 8 images (wave wv = image wv); epilogue
// owns the full 16 B interleaved entry -> fully-coalesced uint4 stores.
//   colp8[i][y] = {img01, img23, img45, img67}  (uint4 entries)
// Grid (12 y, 23 i) = 276 blocks x 512 thr.
// ---------------------------------------------------------------------------
__global__ __launch_bounds__(512)
void filt_gemm_kernel(const uint4* __restrict__ rcC, const uint4* __restrict__ Bg,
                      uint4* __restrict__ colp8) {
    __shared__ _Float16 lx[16][64][8];   // 16 KB

    const int i0 = blockIdx.y * 16;   // angle-tile base
    const int y0 = blockIdx.x * 64;   // y-tile base
    const int wv = threadIdx.x >> 6;  // wave 0..7 = image
    const int L  = threadIdx.x & 63;  // lane

    const int c0 = (y0 / 32 + 20) % NC;   // first band chunk: (y0-128)/32 mod 24
    const uint4* An = rcC + (size_t)wv * NC * IPAD * 4;
    const int arow = i0 + (L & 15);
    const int aoff = L >> 4;

    f32x4 acc[4];
#pragma unroll
    for (int j = 0; j < 4; ++j) acc[j] = (f32x4){0.f, 0.f, 0.f, 0.f};

    for (int t = 0; t < KSTEPS; ++t) {
        int c = c0 + t;
        c -= (c >= NC) ? NC : 0;
        short8 a = __builtin_bit_cast(short8, An[((size_t)c * IPAD + arow) * 4 + aoff]);
#pragma unroll
        for (int j = 0; j < 4; ++j) {
            short8 b = __builtin_bit_cast(short8, Bg[(t * 4 + j) * 64 + L]);
            acc[j] = __builtin_amdgcn_mfma_f32_16x16x32_bf16(a, b, acc[j], 0, 0, 0);
        }
    }

    // exchange: D row=(L>>4)*4+r -> local i, col=L&15 -> local y (within frag j)
#pragma unroll
    for (int j = 0; j < 4; ++j) {
#pragma unroll
        for (int r = 0; r < 4; ++r) {
            int ilc = (L >> 4) * 4 + r;
            int ylc = j * 16 + (L & 15);
            lx[ilc][ylc][wv] = (_Float16)(acc[j][r] * SC);
        }
    }
    __syncthreads();

    // fully-coalesced 16 B stores: entry (i, y) = all 8 images
#pragma unroll
    for (int k = 0; k < 2; ++k) {
        int e = threadIdx.x + k * 512;   // 0..1023
        int ilc = e >> 6, ylc = e & 63;
        int ig = i0 + ilc;
        if (ig < W) {
            colp8[(size_t)ig * H + y0 + ylc] = *(const uint4*)&lx[ilc][ylc][0];
        }
    }
}

// ---------------------------------------------------------------------------
// Kernel 5: backprojection, ALL 8 images/block. Round-6 delta on the proven
// structure: SHARED-WINDOW TAP READS via u-stride-1 sample pairing.
// B = -sin*r^ in (-1, 0], so samples at u and u+1 have py1 = py0 + B and
// iy1 in {iy0-1, iy0}: both samples' 4 taps lie in the 3 consecutive
// entries [iy0-1, iy0+1]. Read the 3-entry window (3 ds_read_b128 instead
// of 4) and select r1's tap pair with 8 v_cndmask on (iy1 < iy0). Taps are
// bit-identical to the per-sample version -> zero numeric change. Trades
// -12 cyc on the 76%-loaded LDS pipe for +16 cyc on the 20%-loaded VALU.
// Sample mapping: u = u0 + 16p + 2*tu + r (pure relabel; epilogue index
// updated). Round-4 lesson: do NOT grow accumulator state (spills); window
// regs are transient, VGPR ~55 < 64 (8-wave boundary).
// 45 angles/block, aq = bid&7 = XCD id. Grid 1024 x 512 thr.
// ---------------------------------------------------------------------------
__global__ __launch_bounds__(512, 6)
void backproj_kernel(const uint4* __restrict__ colp8,
                     const float2* __restrict__ angv, float* __restrict__ outb) {
    __shared__ __align__(16) uint4 colh[2][H];   // 24 KB

    const int bid = blockIdx.x;
    const int aq  = bid & 7;             // XCD-local under round-robin dispatch
    const int tle = bid >> 3;            // 0..127: 16 u-tiles x 8 v-tiles
    const int a0 = aq * (W / 8);         // 45 angles per block
    const int u0 = (tle >> 3) * 32;
    const int v0 = (tle & 7) * 64;
    const int tid = threadIdx.x;
    const int lane = tid & 63;
    const int tu = tid >> 6;             // 0..7

    const float vf = (float)(v0 + lane - D / 2);
    float ufp[2];                        // pair-base u: u0 + 16p + 2*tu
#pragma unroll
    for (int p = 0; p < 2; ++p) ufp[p] = (float)(u0 + 16 * p + 2 * tu - D / 2);

    const h2 hz = {(__fp16)0.f, (__fp16)0.f};
    float acc[4][8];                     // fp32 accumulators [s][img], s=2p+r
    h2 hacc[4][4];                       // fp16 packed partials [s][pair]
#pragma unroll
    for (int s = 0; s < 4; ++s) {
#pragma unroll
        for (int nn = 0; nn < 8; ++nn) acc[s][nn] = 0.f;
#pragma unroll
        for (int p = 0; p < 4; ++p) hacc[s][p] = hz;
    }

    const int y1 = tid;                  // 0..511
    const int y2 = tid + 512;            // 512..767 (tid < 256 only)

    // prologue: stage angle a0 into buffer 0
    {
        const size_t ab = (size_t)a0 * H;
        colh[0][y1] = colp8[ab + y1];
        if (tid < 256) colh[0][y2] = colp8[ab + y2];
    }
    __syncthreads();

    for (int j = 0; j < W / 8; ++j) {
        int a = a0 + j;
        // prefetch next angle's packed column into registers
        int an = (j + 1 < W / 8) ? (a + 1) : a;
        const size_t ab = (size_t)an * H;
        uint4 d = colp8[ab + y1];
        uint4 e = make_uint4(0u, 0u, 0u, 0u);
        if (tid < 256) e = colp8[ab + y2];

        const int cb2 = j & 1;
        float2 AB = angv[a];
        float base = fmaf(vf, AB.x, SY);
#pragma unroll
        for (int p = 0; p < 2; ++p) {
            float py0 = fmaf(ufp[p], AB.y, base);
            float py1 = py0 + AB.y;                    // u+1 sample (B <= 0)
            int iy0 = (int)py0;                        // trunc == floor (py > 0)
            int iy1 = (int)py1;                        // iy1 in {iy0-1, iy0}
            float wy0 = __builtin_amdgcn_fractf(py0);
            float wy1 = __builtin_amdgcn_fractf(py1);
            // 3-entry shared window [iy0-1, iy0+1] (iy0 >= 1 by geometry)
            uint4 e0 = colh[cb2][iy0 - 1];             // ds_read_b128
            uint4 e1 = colh[cb2][iy0];                 // ds_read_b128
            uint4 e2 = colh[cb2][iy0 + 1];             // ds_read_b128
            bool sb = iy1 < iy0;
            uint4 lo1 = sel4(sb, e0, e1);              // 4 cndmask
            uint4 hi1 = sel4(sb, e1, e2);              // 4 cndmask
            h2 w0 = __builtin_amdgcn_cvt_pkrtz(wy0, wy0);
            h2 w1 = __builtin_amdgcn_cvt_pkrtz(wy1, wy1);
            const int s0 = 2 * p, s1 = 2 * p + 1;
            {
                h2 lo = __builtin_bit_cast(h2, e1.x), hi = __builtin_bit_cast(h2, e2.x);
                hacc[s0][0] += lo + w0 * (hi - lo);
                lo = __builtin_bit_cast(h2, lo1.x); hi = __builtin_bit_cast(h2, hi1.x);
                hacc[s1][0] += lo + w1 * (hi - lo);
            }
            {
                h2 lo = __builtin_bit_cast(h2, e1.y), hi = __builtin_bit_cast(h2, e2.y);
                hacc[s0][1] += lo + w0 * (hi - lo);
                lo = __builtin_bit_cast(h2, lo1.y); hi = __builtin_bit_cast(h2, hi1.y);
                hacc[s1][1] += lo + w1 * (hi - lo);
            }
            {
                h2 lo = __builtin_bit_cast(h2, e1.z), hi = __builtin_bit_cast(h2, e2.z);
                hacc[s0][2] += lo + w0 * (hi - lo);
                lo = __builtin_bit_cast(h2, lo1.z); hi = __builtin_bit_cast(h2, hi1.z);
                hacc[s1][2] += lo + w1 * (hi - lo);
            }
            {
                h2 lo = __builtin_bit_cast(h2, e1.w), hi = __builtin_bit_cast(h2, e2.w);
                hacc[s0][3] += lo + w0 * (hi - lo);
                lo = __builtin_bit_cast(h2, lo1.w); hi = __builtin_bit_cast(h2, hi1.w);
                hacc[s1][3] += lo + w1 * (hi - lo);
            }
        }

        // flush fp16 partials to fp32 every 16 angles
        if ((j & 15) == 15) {
#pragma unroll
            for (int s = 0; s < 4; ++s) {
#pragma unroll
                for (int p = 0; p < 4; ++p) {
                    acc[s][2 * p]     += (float)hacc[s][p].x;
                    acc[s][2 * p + 1] += (float)hacc[s][p].y;
                    hacc[s][p] = hz;
                }
            }
        }

        // write prefetched angle into the other buffer (disjoint from read buf)
        colh[cb2 ^ 1][y1] = d;
        if (tid < 256) colh[cb2 ^ 1][y2] = e;
        __syncthreads();
    }

    // final flush + atomic accumulate into output (8 adds/element total)
#pragma unroll
    for (int s = 0; s < 4; ++s) {
#pragma unroll
        for (int p = 0; p < 4; ++p) {
            acc[s][2 * p]     += (float)hacc[s][p].x;
            acc[s][2 * p + 1] += (float)hacc[s][p].y;
        }
        int u = u0 + 16 * (s >> 1) + 2 * tu + (s & 1);
#pragma unroll
        for (int nn = 0; nn < 8; ++nn) {
            size_t idx = ((size_t)nn * D + u) * D + v0 + lane;
            atomicAdd(&outb[idx], acc[s][nn]);
        }
    }
}

// ---------------------------------------------------------------------------
// Workspace layout:
//   [0, 3072)              g (768 floats)
//   [4096, 6976)           ang (360 float2)
//   [8192, 49152)          Bg (2560 uint4 = 40 KB B-frag table)
//   [65536, 4489216)       colp8 (360 x 768 x 16B interleaved fp16 columns)
//   [4489216, 9207808)     rcC (8 x 24 x 384 x 64B bf16 A-frag chunks)
// ---------------------------------------------------------------------------
extern "C" void kernel_launch(void* const* d_in, const int* in_sizes, int n_in,
                              void* d_out, int out_size, void* d_ws, size_t ws_size,
                              hipStream_t stream) {
    const float* radon = (const float*)d_in[0];
    const float* hG    = (const float*)d_in[1];
    float* out = (float*)d_out;

    float*  g    = (float*)d_ws;
    float2* ang  = (float2*)((char*)d_ws + 4096);
    uint4*  Bg   = (uint4*)((char*)d_ws + 8192);
    uint4*  colp8 = (uint4*)((char*)d_ws + 65536);
    uint4*  rcC  = (uint4*)((char*)d_ws + 4489216);

    build_g_kernel<<<H, 64, 0, stream>>>(hG, g);
    build_angbg_kernel<<<41, 64, 0, stream>>>(g, Bg, ang);
    build_rc_kernel<<<dim3(6, NC, N_IMG), 256, 0, stream>>>(radon, rcC, (float4*)out);
    filt_gemm_kernel<<<dim3(H / 64, 23), 512, 0, stream>>>(rcC, Bg, colp8);
    backproj_kernel<<<1024, 512, 0, stream>>>(colp8, ang, out);
}

// Round 7
// 175.924 us; speedup vs baseline: 1.0516x; 1.0516x over previous
//
#include <hip/hip_runtime.h>
#include <math.h>

// Problem constants (from setup_inputs): N=8, H=768, W=360, D=512
#define N_IMG 8
#define H 768
#define W 360
#define D 512
#define SY 383.5f         // (H-1)/2
#define SC 0.00436332312998582394f  // pi/(2W) = pi/720
#define NC 24             // 768/32 m-chunks
#define IPAD 384          // i dimension padded 360 -> 384

typedef __fp16 h2 __attribute__((ext_vector_type(2)));
typedef short short8 __attribute__((ext_vector_type(8)));   // 8 bf16 (4 VGPRs)
typedef float f32x4 __attribute__((ext_vector_type(4)));

// async global->LDS, 16 B per lane (dest must be linear: base + lane*16)
#define GLOAD_LDS16(g, l)                                                      \
    __builtin_amdgcn_global_load_lds(                                          \
        (const __attribute__((address_space(1))) unsigned int*)(const void*)(g), \
        (__attribute__((address_space(3))) unsigned int*)(void*)(l), 16, 0, 0)

// fp32 -> bf16 pair, round-to-nearest-even, packed into one uint
__device__ inline unsigned bf16pair(float a, float b) {
    unsigned ua = __builtin_bit_cast(unsigned, a);
    unsigned ub = __builtin_bit_cast(unsigned, b);
    ua += 0x7FFFu + ((ua >> 16) & 1u);
    ub += 0x7FFFu + ((ub >> 16) & 1u);
    return (ua >> 16) | (ub & 0xFFFF0000u);
}

// ---------------------------------------------------------------------------
// Kernel 1: g[m] = (1/H) sum_k hG[k] * cos(2*pi*k*m/H)
// ---------------------------------------------------------------------------
__global__ void build_g_kernel(const float* __restrict__ hG, float* __restrict__ g) {
    int m = blockIdx.x;          // 0..767
    int lane = threadIdx.x;      // 0..63
    float s = 0.f;
#pragma unroll
    for (int q = 0; q < 12; ++q) {
        int k = lane + 64 * q;
        int prod = (k * m) % H;  // exact periodic reduction
        float angr = (float)prod * 0.00818123086872313911f;  // 2*pi/768
        s += hG[k] * cosf(angr);
    }
#pragma unroll
    for (int off = 32; off > 0; off >>= 1) s += __shfl_down(s, off);
    if (lane == 0) g[m] = s * (1.0f / (float)H);
}

// ---------------------------------------------------------------------------
// Kernel 2 (fused): blocks 0-39 build the MFMA B-frag table
// Bg[(t*4+j)*64+L] (n = j*16+(L&15), k = 32t+(L>>4)*8+s, val g[(n+128-k)%H]);
// block 40 builds per-angle constants ang[i] = (cos*r, -sin*r).
// ---------------------------------------------------------------------------
#define KSTEPS 10          // 10 x 32 = K 320 band

__global__ void build_angbg_kernel(const float* __restrict__ g, uint4* __restrict__ Bg,
                                   float2* __restrict__ ang) {
    int b = blockIdx.x;
    int t = threadIdx.x;
    if (b < 40) {
        int idx = b * 64 + t;       // 0..2559
        int L  = idx & 63;
        int tj = idx >> 6;          // t*4 + j
        int nn = (tj & 3) * 16 + (L & 15);
        int kb = (tj >> 2) * 32 + (L >> 4) * 8;
        float bf[8];
#pragma unroll
        for (int s = 0; s < 8; ++s) {
            int d = nn + 128 - (kb + s);
            d += (d < 0) ? H : 0;
            bf[s] = g[d];
        }
        Bg[idx] = (uint4){bf16pair(bf[0], bf[1]), bf16pair(bf[2], bf[3]),
                          bf16pair(bf[4], bf[5]), bf16pair(bf[6], bf[7])};
    } else {
#pragma unroll
        for (int q = 0; q < 6; ++q) {
            int i = t + 64 * q;
            if (i < W) {
                float th = (float)i * 0.00872664625997164788f;  // pi/360
                float r = SY / 384.0f;
                ang[i] = make_float2(cosf(th) * r, -sinf(th) * r);
            }
        }
    }
}

// ---------------------------------------------------------------------------
// Kernel 3: A-matrix transpose + bf16 pack (+ fused output zeroing).
// px = (tx_i+1)*sx == i exactly -> rc[n][i][m] = radon[n][m][i]: pure
// transpose. Block (i-tile 64, chunk c, image n): coalesced float4 row loads
// -> LDS (pad 65) -> transposed bf16x8 pack -> contiguous uint4 store.
// Blocks with flat id < 1024 also zero 2 KB of the output (atomic target).
// Grid (6, 24, 8) = 1152 blocks x 256 thr.
// ---------------------------------------------------------------------------
__global__ __launch_bounds__(256)
void build_rc_kernel(const float* __restrict__ radon, uint4* __restrict__ rcC,
                     float4* __restrict__ out4) {
    __shared__ float xs[32][65];   // 8.3 KB

    const int i0 = blockIdx.x * 64;
    const int c  = blockIdx.y;
    const int n  = blockIdx.z;
    const int tid = threadIdx.x;

    // fused zero of the atomic output (1024 blocks x 512 float4 = full 8 MB)
    {
        int flat = ((n * NC) + c) * 6 + blockIdx.x;
        if (flat < 1024) {
            out4[flat * 512 + tid]       = make_float4(0.f, 0.f, 0.f, 0.f);
            out4[flat * 512 + 256 + tid] = make_float4(0.f, 0.f, 0.f, 0.f);
        }
    }

    // load radon[m = 32c + mr][i0 + lane8*8 .. +8) coalesced
    {
        int mr    = tid >> 3;      // 0..31
        int lane8 = tid & 7;
        int ib = i0 + lane8 * 8;
        const float* src = radon + ((size_t)n * H + 32 * c + mr) * W + ib;
        float4 v0, v1;
        if (ib + 7 < W) {          // 360 % 8 == 0: tiles all-valid or all-invalid
            v0 = *(const float4*)src;
            v1 = *(const float4*)(src + 4);
        } else {
            v0 = make_float4(0.f, 0.f, 0.f, 0.f);
            v1 = make_float4(0.f, 0.f, 0.f, 0.f);
        }
        *(float4*)&xs[mr][lane8 * 8]     = v0;
        *(float4*)&xs[mr][lane8 * 8 + 4] = v1;
    }
    __syncthreads();

    // transposed pack: 8 m-values (oct) for angle i0+il
    const int il  = tid >> 2;      // 0..63
    const int oct = tid & 3;
    float v[8];
#pragma unroll
    for (int s = 0; s < 8; ++s) v[s] = xs[oct * 8 + s][il];
    uint4 pk = {bf16pair(v[0], v[1]), bf16pair(v[2], v[3]),
                bf16pair(v[4], v[5]), bf16pair(v[6], v[7])};
    rcC[(((size_t)n * NC + c) * IPAD + i0 + il) * 4 + oct] = pk;
}

// ---------------------------------------------------------------------------
// Kernel 4: banded circulant filtering, barrier-free MFMA GEMM.
// ONE 512-thread block covers all 8 images (wave wv = image wv); epilogue
// owns the full 16 B interleaved entry -> fully-coalesced uint4 stores.
//   colp8[i][y] = {img01, img23, img45, img67}  (uint4 entries)
// Grid (12 y, 23 i) = 276 blocks x 512 thr.
// ---------------------------------------------------------------------------
__global__ __launch_bounds__(512)
void filt_gemm_kernel(const uint4* __restrict__ rcC, const uint4* __restrict__ Bg,
                      uint4* __restrict__ colp8) {
    __shared__ _Float16 lx[16][64][8];   // 16 KB

    const int i0 = blockIdx.y * 16;   // angle-tile base
    const int y0 = blockIdx.x * 64;   // y-tile base
    const int wv = threadIdx.x >> 6;  // wave 0..7 = image
    const int L  = threadIdx.x & 63;  // lane

    const int c0 = (y0 / 32 + 20) % NC;   // first band chunk: (y0-128)/32 mod 24
    const uint4* An = rcC + (size_t)wv * NC * IPAD * 4;
    const int arow = i0 + (L & 15);
    const int aoff = L >> 4;

    f32x4 acc[4];
#pragma unroll
    for (int j = 0; j < 4; ++j) acc[j] = (f32x4){0.f, 0.f, 0.f, 0.f};

    for (int t = 0; t < KSTEPS; ++t) {
        int c = c0 + t;
        c -= (c >= NC) ? NC : 0;
        short8 a = __builtin_bit_cast(short8, An[((size_t)c * IPAD + arow) * 4 + aoff]);
#pragma unroll
        for (int j = 0; j < 4; ++j) {
            short8 b = __builtin_bit_cast(short8, Bg[(t * 4 + j) * 64 + L]);
            acc[j] = __builtin_amdgcn_mfma_f32_16x16x32_bf16(a, b, acc[j], 0, 0, 0);
        }
    }

    // exchange: D row=(L>>4)*4+r -> local i, col=L&15 -> local y (within frag j)
#pragma unroll
    for (int j = 0; j < 4; ++j) {
#pragma unroll
        for (int r = 0; r < 4; ++r) {
            int ilc = (L >> 4) * 4 + r;
            int ylc = j * 16 + (L & 15);
            lx[ilc][ylc][wv] = (_Float16)(acc[j][r] * SC);
        }
    }
    __syncthreads();

    // fully-coalesced 16 B stores: entry (i, y) = all 8 images
#pragma unroll
    for (int k = 0; k < 2; ++k) {
        int e = threadIdx.x + k * 512;   // 0..1023
        int ilc = e >> 6, ylc = e & 63;
        int ig = i0 + ilc;
        if (ig < W) {
            colp8[(size_t)ig * H + y0 + ylc] = *(const uint4*)&lx[ilc][ylc][0];
        }
    }
}

// ---------------------------------------------------------------------------
// Kernel 5: backprojection, ALL 8 images/block. Round-7 delta on the proven
// round-5 structure (101.5 us): staging via __builtin_amdgcn_global_load_lds
// width-16 instead of VMEM->reg->ds_write. Issued at the TOP of iteration j
// into buf cb2^1 (last read before the previous barrier -> safe); the
// __syncthreads at iteration end drains vmcnt (compiler-guaranteed), so
// loads stay in flight across the whole compute phase. Removes 1.5
// ds_write_b128/thread/angle (-13% LDS-pipe work), the register round-trip,
// and ~8 prefetch VGPRs. Dest is linear (colh[buf][tid], lane-contiguous
// 16 B, wave-uniform base) as required. Inner loop untouched (round-2/6
// lessons: read-structure changes backfire via conflicts).
// 45 angles/block, aq = bid&7 = XCD id. Grid 1024 x 512 thr.
// ---------------------------------------------------------------------------
__global__ __launch_bounds__(512, 6)
void backproj_kernel(const uint4* __restrict__ colp8,
                     const float2* __restrict__ angv, float* __restrict__ outb) {
    __shared__ __align__(16) uint4 colh[2][H];   // 24 KB

    const int bid = blockIdx.x;
    const int aq  = bid & 7;             // XCD-local under round-robin dispatch
    const int tle = bid >> 3;            // 0..127: 16 u-tiles x 8 v-tiles
    const int a0 = aq * (W / 8);         // 45 angles per block
    const int u0 = (tle >> 3) * 32;
    const int v0 = (tle & 7) * 64;
    const int tid = threadIdx.x;
    const int lane = tid & 63;
    const int tu = tid >> 6;             // 0..7

    const float vf = (float)(v0 + lane - D / 2);
    float uf[4];
#pragma unroll
    for (int r = 0; r < 4; ++r) uf[r] = (float)(u0 + tu + 8 * r - D / 2);

    const h2 hz = {(__fp16)0.f, (__fp16)0.f};
    float acc[4][8];                     // fp32 accumulators [r][img]
    h2 hacc[4][4];                       // fp16 packed partials [r][pair]
#pragma unroll
    for (int r = 0; r < 4; ++r) {
#pragma unroll
        for (int nn = 0; nn < 8; ++nn) acc[r][nn] = 0.f;
#pragma unroll
        for (int p = 0; p < 4; ++p) hacc[r][p] = hz;
    }

    const int y1 = tid;                  // 0..511
    const int y2 = tid + 512;            // 512..767 (tid < 256 only)

    // prologue: stage angle a0 into buffer 0 (async direct-to-LDS)
    {
        const size_t ab = (size_t)a0 * H;
        GLOAD_LDS16(colp8 + ab + y1, &colh[0][y1]);
        if (tid < 256) GLOAD_LDS16(colp8 + ab + y2, &colh[0][y2]);
    }
    __syncthreads();

    for (int j = 0; j < W / 8; ++j) {
        int a = a0 + j;
        const int cb2 = j & 1;

        // issue next angle's staging into the other buffer (in flight across
        // the compute below; drained by the barrier at iteration end)
        if (j + 1 < W / 8) {
            const size_t ab = (size_t)(a + 1) * H;
            GLOAD_LDS16(colp8 + ab + y1, &colh[cb2 ^ 1][y1]);
            if (tid < 256) GLOAD_LDS16(colp8 + ab + y2, &colh[cb2 ^ 1][y2]);
        }

        float2 AB = angv[a];
        float base = fmaf(vf, AB.x, SY);
#pragma unroll
        for (int r = 0; r < 4; ++r) {
            float py = fmaf(uf[r], AB.y, base);
            float wy = __builtin_amdgcn_fractf(py);
            int iy = (int)py;                          // trunc == floor (py > 0)
            uint4 lo4 = colh[cb2][iy];                 // ds_read_b128: 8 imgs @ y
            uint4 hi4 = colh[cb2][iy + 1];             // ds_read_b128: 8 imgs @ y+1
            h2 wy2 = __builtin_amdgcn_cvt_pkrtz(wy, wy);
            {
                h2 lo = __builtin_bit_cast(h2, lo4.x), hi = __builtin_bit_cast(h2, hi4.x);
                hacc[r][0] += lo + wy2 * (hi - lo);
            }
            {
                h2 lo = __builtin_bit_cast(h2, lo4.y), hi = __builtin_bit_cast(h2, hi4.y);
                hacc[r][1] += lo + wy2 * (hi - lo);
            }
            {
                h2 lo = __builtin_bit_cast(h2, lo4.z), hi = __builtin_bit_cast(h2, hi4.z);
                hacc[r][2] += lo + wy2 * (hi - lo);
            }
            {
                h2 lo = __builtin_bit_cast(h2, lo4.w), hi = __builtin_bit_cast(h2, hi4.w);
                hacc[r][3] += lo + wy2 * (hi - lo);
            }
        }

        // flush fp16 partials to fp32 every 16 angles
        if ((j & 15) == 15) {
#pragma unroll
            for (int r = 0; r < 4; ++r) {
#pragma unroll
                for (int p = 0; p < 4; ++p) {
                    acc[r][2 * p]     += (float)hacc[r][p].x;
                    acc[r][2 * p + 1] += (float)hacc[r][p].y;
                    hacc[r][p] = hz;
                }
            }
        }

        __syncthreads();   // drains vmcnt: staged angle j+1 is now in LDS
    }

    // final flush + atomic accumulate into output (8 adds/element total)
#pragma unroll
    for (int r = 0; r < 4; ++r) {
#pragma unroll
        for (int p = 0; p < 4; ++p) {
            acc[r][2 * p]     += (float)hacc[r][p].x;
            acc[r][2 * p + 1] += (float)hacc[r][p].y;
        }
        int u = u0 + tu + 8 * r;
#pragma unroll
        for (int nn = 0; nn < 8; ++nn) {
            size_t idx = ((size_t)nn * D + u) * D + v0 + lane;
            atomicAdd(&outb[idx], acc[r][nn]);
        }
    }
}

// ---------------------------------------------------------------------------
// Workspace layout:
//   [0, 3072)              g (768 floats)
//   [4096, 6976)           ang (360 float2)
//   [8192, 49152)          Bg (2560 uint4 = 40 KB B-frag table)
//   [65536, 4489216)       colp8 (360 x 768 x 16B interleaved fp16 columns)
//   [4489216, 9207808)     rcC (8 x 24 x 384 x 64B bf16 A-frag chunks)
// ---------------------------------------------------------------------------
extern "C" void kernel_launch(void* const* d_in, const int* in_sizes, int n_in,
                              void* d_out, int out_size, void* d_ws, size_t ws_size,
                              hipStream_t stream) {
    const float* radon = (const float*)d_in[0];
    const float* hG    = (const float*)d_in[1];
    float* out = (float*)d_out;

    float*  g    = (float*)d_ws;
    float2* ang  = (float2*)((char*)d_ws + 4096);
    uint4*  Bg   = (uint4*)((char*)d_ws + 8192);
    uint4*  colp8 = (uint4*)((char*)d_ws + 65536);
    uint4*  rcC  = (uint4*)((char*)d_ws + 4489216);

    build_g_kernel<<<H, 64, 0, stream>>>(hG, g);
    build_angbg_kernel<<<41, 64, 0, stream>>>(g, Bg, ang);
    build_rc_kernel<<<dim3(6, NC, N_IMG), 256, 0, stream>>>(radon, rcC, (float4*)out);
    filt_gemm_kernel<<<dim3(H / 64, 23), 512, 0, stream>>>(rcC, Bg, colp8);
    backproj_kernel<<<1024, 512, 0, stream>>>(colp8, ang, out);
}

// Round 8
// 168.207 us; speedup vs baseline: 1.0999x; 1.0459x over previous
//
#include <hip/hip_runtime.h>
#include <math.h>

// Problem constants (from setup_inputs): N=8, H=768, W=360, D=512
#define N_IMG 8
#define H 768
#define W 360
#define D 512
#define SY 383.5f         // (H-1)/2
#define SC 0.00436332312998582394f  // pi/(2W) = pi/720
#define NC 24             // 768/32 m-chunks
#define IPAD 384          // i dimension padded 360 -> 384

typedef __fp16 h2 __attribute__((ext_vector_type(2)));
typedef short short8 __attribute__((ext_vector_type(8)));   // 8 bf16 (4 VGPRs)
typedef float f32x4 __attribute__((ext_vector_type(4)));

// async global->LDS, 16 B per lane (dest must be linear: base + lane*16)
#define GLOAD_LDS16(g, l)                                                      \
    __builtin_amdgcn_global_load_lds(                                          \
        (const __attribute__((address_space(1))) unsigned int*)(const void*)(g), \
        (__attribute__((address_space(3))) unsigned int*)(void*)(l), 16, 0, 0)

// fp32 -> bf16 pair, round-to-nearest-even, packed into one uint
__device__ inline unsigned bf16pair(float a, float b) {
    unsigned ua = __builtin_bit_cast(unsigned, a);
    unsigned ub = __builtin_bit_cast(unsigned, b);
    ua += 0x7FFFu + ((ua >> 16) & 1u);
    ub += 0x7FFFu + ((ub >> 16) & 1u);
    return (ua >> 16) | (ub & 0xFFFF0000u);
}

// ---------------------------------------------------------------------------
// Kernel 1: g[m] = (1/H) sum_k hG[k] * cos(2*pi*k*m/H)
// ---------------------------------------------------------------------------
__global__ void build_g_kernel(const float* __restrict__ hG, float* __restrict__ g) {
    int m = blockIdx.x;          // 0..767
    int lane = threadIdx.x;      // 0..63
    float s = 0.f;
#pragma unroll
    for (int q = 0; q < 12; ++q) {
        int k = lane + 64 * q;
        int prod = (k * m) % H;  // exact periodic reduction
        float angr = (float)prod * 0.00818123086872313911f;  // 2*pi/768
        s += hG[k] * cosf(angr);
    }
#pragma unroll
    for (int off = 32; off > 0; off >>= 1) s += __shfl_down(s, off);
    if (lane == 0) g[m] = s * (1.0f / (float)H);
}

// ---------------------------------------------------------------------------
// Kernel 2 (fused): blocks 0-39 build the MFMA B-frag table
// Bg[(t*4+j)*64+L] (n = j*16+(L&15), k = 32t+(L>>4)*8+s, val g[(n+128-k)%H]);
// block 40 builds per-angle constants ang[i] = (cos*r, -sin*r).
// ---------------------------------------------------------------------------
#define KSTEPS 10          // 10 x 32 = K 320 band

__global__ void build_angbg_kernel(const float* __restrict__ g, uint4* __restrict__ Bg,
                                   float2* __restrict__ ang) {
    int b = blockIdx.x;
    int t = threadIdx.x;
    if (b < 40) {
        int idx = b * 64 + t;       // 0..2559
        int L  = idx & 63;
        int tj = idx >> 6;          // t*4 + j
        int nn = (tj & 3) * 16 + (L & 15);
        int kb = (tj >> 2) * 32 + (L >> 4) * 8;
        float bf[8];
#pragma unroll
        for (int s = 0; s < 8; ++s) {
            int d = nn + 128 - (kb + s);
            d += (d < 0) ? H : 0;
            bf[s] = g[d];
        }
        Bg[idx] = (uint4){bf16pair(bf[0], bf[1]), bf16pair(bf[2], bf[3]),
                          bf16pair(bf[4], bf[5]), bf16pair(bf[6], bf[7])};
    } else {
#pragma unroll
        for (int q = 0; q < 6; ++q) {
            int i = t + 64 * q;
            if (i < W) {
                float th = (float)i * 0.00872664625997164788f;  // pi/360
                float r = SY / 384.0f;
                ang[i] = make_float2(cosf(th) * r, -sinf(th) * r);
            }
        }
    }
}

// ---------------------------------------------------------------------------
// Kernel 3: A-matrix transpose + bf16 pack (+ fused output zeroing).
// px = (tx_i+1)*sx == i exactly -> rc[n][i][m] = radon[n][m][i]: pure
// transpose. Block (i-tile 64, chunk c, image n): coalesced float4 row loads
// -> LDS (pad 65) -> transposed bf16x8 pack -> contiguous uint4 store.
// Blocks with flat id < 1024 also zero 2 KB of the output (atomic target).
// Grid (6, 24, 8) = 1152 blocks x 256 thr.
// ---------------------------------------------------------------------------
__global__ __launch_bounds__(256)
void build_rc_kernel(const float* __restrict__ radon, uint4* __restrict__ rcC,
                     float4* __restrict__ out4) {
    __shared__ float xs[32][65];   // 8.3 KB

    const int i0 = blockIdx.x * 64;
    const int c  = blockIdx.y;
    const int n  = blockIdx.z;
    const int tid = threadIdx.x;

    // fused zero of the atomic output (1024 blocks x 512 float4 = full 8 MB)
    {
        int flat = ((n * NC) + c) * 6 + blockIdx.x;
        if (flat < 1024) {
            out4[flat * 512 + tid]       = make_float4(0.f, 0.f, 0.f, 0.f);
            out4[flat * 512 + 256 + tid] = make_float4(0.f, 0.f, 0.f, 0.f);
        }
    }

    // load radon[m = 32c + mr][i0 + lane8*8 .. +8) coalesced
    {
        int mr    = tid >> 3;      // 0..31
        int lane8 = tid & 7;
        int ib = i0 + lane8 * 8;
        const float* src = radon + ((size_t)n * H + 32 * c + mr) * W + ib;
        float4 v0, v1;
        if (ib + 7 < W) {          // 360 % 8 == 0: tiles all-valid or all-invalid
            v0 = *(const float4*)src;
            v1 = *(const float4*)(src + 4);
        } else {
            v0 = make_float4(0.f, 0.f, 0.f, 0.f);
            v1 = make_float4(0.f, 0.f, 0.f, 0.f);
        }
        *(float4*)&xs[mr][lane8 * 8]     = v0;
        *(float4*)&xs[mr][lane8 * 8 + 4] = v1;
    }
    __syncthreads();

    // transposed pack: 8 m-values (oct) for angle i0+il
    const int il  = tid >> 2;      // 0..63
    const int oct = tid & 3;
    float v[8];
#pragma unroll
    for (int s = 0; s < 8; ++s) v[s] = xs[oct * 8 + s][il];
    uint4 pk = {bf16pair(v[0], v[1]), bf16pair(v[2], v[3]),
                bf16pair(v[4], v[5]), bf16pair(v[6], v[7])};
    rcC[(((size_t)n * NC + c) * IPAD + i0 + il) * 4 + oct] = pk;
}

// ---------------------------------------------------------------------------
// Kernel 4: banded circulant filtering, barrier-free MFMA GEMM.
// ONE 512-thread block covers all 8 images (wave wv = image wv); epilogue
// owns the full 16 B interleaved entry -> fully-coalesced uint4 stores.
//   colp8[i][y] = {img01, img23, img45, img67}  (uint4 entries)
// Grid (12 y, 23 i) = 276 blocks x 512 thr.
// ---------------------------------------------------------------------------
__global__ __launch_bounds__(512)
void filt_gemm_kernel(const uint4* __restrict__ rcC, const uint4* __restrict__ Bg,
                      uint4* __restrict__ colp8) {
    __shared__ _Float16 lx[16][64][8];   // 16 KB

    const int i0 = blockIdx.y * 16;   // angle-tile base
    const int y0 = blockIdx.x * 64;   // y-tile base
    const int wv = threadIdx.x >> 6;  // wave 0..7 = image
    const int L  = threadIdx.x & 63;  // lane

    const int c0 = (y0 / 32 + 20) % NC;   // first band chunk: (y0-128)/32 mod 24
    const uint4* An = rcC + (size_t)wv * NC * IPAD * 4;
    const int arow = i0 + (L & 15);
    const int aoff = L >> 4;

    f32x4 acc[4];
#pragma unroll
    for (int j = 0; j < 4; ++j) acc[j] = (f32x4){0.f, 0.f, 0.f, 0.f};

    for (int t = 0; t < KSTEPS; ++t) {
        int c = c0 + t;
        c -= (c >= NC) ? NC : 0;
        short8 a = __builtin_bit_cast(short8, An[((size_t)c * IPAD + arow) * 4 + aoff]);
#pragma unroll
        for (int j = 0; j < 4; ++j) {
            short8 b = __builtin_bit_cast(short8, Bg[(t * 4 + j) * 64 + L]);
            acc[j] = __builtin_amdgcn_mfma_f32_16x16x32_bf16(a, b, acc[j], 0, 0, 0);
        }
    }

    // exchange: D row=(L>>4)*4+r -> local i, col=L&15 -> local y (within frag j)
#pragma unroll
    for (int j = 0; j < 4; ++j) {
#pragma unroll
        for (int r = 0; r < 4; ++r) {
            int ilc = (L >> 4) * 4 + r;
            int ylc = j * 16 + (L & 15);
            lx[ilc][ylc][wv] = (_Float16)(acc[j][r] * SC);
        }
    }
    __syncthreads();

    // fully-coalesced 16 B stores: entry (i, y) = all 8 images
#pragma unroll
    for (int k = 0; k < 2; ++k) {
        int e = threadIdx.x + k * 512;   // 0..1023
        int ilc = e >> 6, ylc = e & 63;
        int ig = i0 + ilc;
        if (ig < W) {
            colp8[(size_t)ig * H + y0 + ylc] = *(const uint4*)&lx[ilc][ylc][0];
        }
    }
}

// ---------------------------------------------------------------------------
// Kernel 5: backprojection, ALL 8 images/block. Round-8 delta: 2-ANGLE
// EPOCHS. Stage a PAIR of angles per buffer half (colh[buf][slot][y],
// 48 KB) via global_load_lds; ONE barrier per pair -> syncs 46 -> 24.
// The two angles' compute chains are independent (2x ILP per epoch to
// cover ds_read latency); barrier drain amortized over 2x work. Flush
// cadence (e&7)==7 = every 16 angles -> numerically identical order.
// Traffic identical to round 7 (full columns, no windows). Inner read
// structure untouched (rounds 2/6: changes there backfire via conflicts).
// 45 angles/block = 22 pairs + 1 tail, aq = bid&7 = XCD id.
// Grid 1024 x 512 thr.
// ---------------------------------------------------------------------------
#define NEPOCH 23          // ceil(45 / 2)

__global__ __launch_bounds__(512, 6)
void backproj_kernel(const uint4* __restrict__ colp8,
                     const float2* __restrict__ angv, float* __restrict__ outb) {
    __shared__ __align__(16) uint4 colh[2][2][H];   // 48 KB: [buf][slot][y]

    const int bid = blockIdx.x;
    const int aq  = bid & 7;             // XCD-local under round-robin dispatch
    const int tle = bid >> 3;            // 0..127: 16 u-tiles x 8 v-tiles
    const int a0 = aq * (W / 8);         // 45 angles per block
    const int u0 = (tle >> 3) * 32;
    const int v0 = (tle & 7) * 64;
    const int tid = threadIdx.x;
    const int lane = tid & 63;
    const int tu = tid >> 6;             // 0..7

    const float vf = (float)(v0 + lane - D / 2);
    float uf[4];
#pragma unroll
    for (int r = 0; r < 4; ++r) uf[r] = (float)(u0 + tu + 8 * r - D / 2);

    const h2 hz = {(__fp16)0.f, (__fp16)0.f};
    float acc[4][8];                     // fp32 accumulators [r][img]
    h2 hacc[4][4];                       // fp16 packed partials [r][pair]
#pragma unroll
    for (int r = 0; r < 4; ++r) {
#pragma unroll
        for (int nn = 0; nn < 8; ++nn) acc[r][nn] = 0.f;
#pragma unroll
        for (int p = 0; p < 4; ++p) hacc[r][p] = hz;
    }

    const int y1 = tid;                  // 0..511
    const int y2 = tid + 512;            // 512..767 (tid < 256 only)

    // prologue: stage angle pair (a0, a0+1) into buffer 0
    {
        GLOAD_LDS16(colp8 + (size_t)a0 * H + y1,       &colh[0][0][y1]);
        GLOAD_LDS16(colp8 + (size_t)(a0 + 1) * H + y1, &colh[0][1][y1]);
        if (tid < 256) {
            GLOAD_LDS16(colp8 + (size_t)a0 * H + y2,       &colh[0][0][y2]);
            GLOAD_LDS16(colp8 + (size_t)(a0 + 1) * H + y2, &colh[0][1][y2]);
        }
    }
    __syncthreads();

    for (int e = 0; e < NEPOCH; ++e) {
        const int cb = e & 1;

        // issue next pair's staging into the other buffer (in flight across
        // the compute below; drained by the barrier at epoch end)
        if (e + 1 < NEPOCH) {
            const int a1 = a0 + 2 * e + 2;
            GLOAD_LDS16(colp8 + (size_t)a1 * H + y1, &colh[cb ^ 1][0][y1]);
            if (2 * e + 3 < 45)
                GLOAD_LDS16(colp8 + (size_t)(a1 + 1) * H + y1, &colh[cb ^ 1][1][y1]);
            if (tid < 256) {
                GLOAD_LDS16(colp8 + (size_t)a1 * H + y2, &colh[cb ^ 1][0][y2]);
                if (2 * e + 3 < 45)
                    GLOAD_LDS16(colp8 + (size_t)(a1 + 1) * H + y2, &colh[cb ^ 1][1][y2]);
            }
        }

        // compute the pair (independent chains -> 2x ILP per epoch)
#pragma unroll
        for (int s = 0; s < 2; ++s) {
            const int jj = 2 * e + s;
            if (jj < 45) {
                const int a = a0 + jj;
                float2 AB = angv[a];
                float base = fmaf(vf, AB.x, SY);
#pragma unroll
                for (int r = 0; r < 4; ++r) {
                    float py = fmaf(uf[r], AB.y, base);
                    float wy = __builtin_amdgcn_fractf(py);
                    int iy = (int)py;                  // trunc == floor (py > 0)
                    uint4 lo4 = colh[cb][s][iy];       // ds_read_b128: 8 imgs @ y
                    uint4 hi4 = colh[cb][s][iy + 1];   // ds_read_b128: 8 imgs @ y+1
                    h2 wy2 = __builtin_amdgcn_cvt_pkrtz(wy, wy);
                    {
                        h2 lo = __builtin_bit_cast(h2, lo4.x), hi = __builtin_bit_cast(h2, hi4.x);
                        hacc[r][0] += lo + wy2 * (hi - lo);
                    }
                    {
                        h2 lo = __builtin_bit_cast(h2, lo4.y), hi = __builtin_bit_cast(h2, hi4.y);
                        hacc[r][1] += lo + wy2 * (hi - lo);
                    }
                    {
                        h2 lo = __builtin_bit_cast(h2, lo4.z), hi = __builtin_bit_cast(h2, hi4.z);
                        hacc[r][2] += lo + wy2 * (hi - lo);
                    }
                    {
                        h2 lo = __builtin_bit_cast(h2, lo4.w), hi = __builtin_bit_cast(h2, hi4.w);
                        hacc[r][3] += lo + wy2 * (hi - lo);
                    }
                }
            }
        }

        // flush fp16 partials to fp32 every 8 epochs (= 16 angles, as before)
        if ((e & 7) == 7) {
#pragma unroll
            for (int r = 0; r < 4; ++r) {
#pragma unroll
                for (int p = 0; p < 4; ++p) {
                    acc[r][2 * p]     += (float)hacc[r][p].x;
                    acc[r][2 * p + 1] += (float)hacc[r][p].y;
                    hacc[r][p] = hz;
                }
            }
        }

        __syncthreads();   // drains vmcnt: staged pair e+1 is now in LDS
    }

    // final flush + atomic accumulate into output (8 adds/element total)
#pragma unroll
    for (int r = 0; r < 4; ++r) {
#pragma unroll
        for (int p = 0; p < 4; ++p) {
            acc[r][2 * p]     += (float)hacc[r][p].x;
            acc[r][2 * p + 1] += (float)hacc[r][p].y;
        }
        int u = u0 + tu + 8 * r;
#pragma unroll
        for (int nn = 0; nn < 8; ++nn) {
            size_t idx = ((size_t)nn * D + u) * D + v0 + lane;
            atomicAdd(&outb[idx], acc[r][nn]);
        }
    }
}

// ---------------------------------------------------------------------------
// Workspace layout:
//   [0, 3072)              g (768 floats)
//   [4096, 6976)           ang (360 float2)
//   [8192, 49152)          Bg (2560 uint4 = 40 KB B-frag table)
//   [65536, 4489216)       colp8 (360 x 768 x 16B interleaved fp16 columns)
//   [4489216, 9207808)     rcC (8 x 24 x 384 x 64B bf16 A-frag chunks)
// ---------------------------------------------------------------------------
extern "C" void kernel_launch(void* const* d_in, const int* in_sizes, int n_in,
                              void* d_out, int out_size, void* d_ws, size_t ws_size,
                              hipStream_t stream) {
    const float* radon = (const float*)d_in[0];
    const float* hG    = (const float*)d_in[1];
    float* out = (float*)d_out;

    float*  g    = (float*)d_ws;
    float2* ang  = (float2*)((char*)d_ws + 4096);
    uint4*  Bg   = (uint4*)((char*)d_ws + 8192);
    uint4*  colp8 = (uint4*)((char*)d_ws + 65536);
    uint4*  rcC  = (uint4*)((char*)d_ws + 4489216);

    build_g_kernel<<<H, 64, 0, stream>>>(hG, g);
    build_angbg_kernel<<<41, 64, 0, stream>>>(g, Bg, ang);
    build_rc_kernel<<<dim3(6, NC, N_IMG), 256, 0, stream>>>(radon, rcC, (float4*)out);
    filt_gemm_kernel<<<dim3(H / 64, 23), 512, 0, stream>>>(rcC, Bg, colp8);
    backproj_kernel<<<1024, 512, 0, stream>>>(colp8, ang, out);
}